// Round 4
// baseline (335.485 us; speedup 1.0000x reference)
//
#include <hip/hip_runtime.h>
#include <cstdint>

typedef __attribute__((ext_vector_type(8))) short short8_t;  // 8 bf16 (4 VGPRs)
typedef __attribute__((ext_vector_type(4))) float f32x4;

// f32 -> bf16 bits, round-to-nearest-even (inputs are finite; no NaN handling)
static __device__ __forceinline__ unsigned bf16_rne(float x) {
  union { float f; unsigned u; } a; a.f = x;
  return (a.u + 0x7FFFu + ((a.u >> 16) & 1u)) >> 16;
}
static __device__ __forceinline__ unsigned pk2(float lo, float hi) {
  return bf16_rne(lo) | (bf16_rne(hi) << 16);
}

// ---------------------------------------------------------------------------
// K1: 1x1 conv 256->8 on 64x64 maps. x[4,256,64,64] * w[8,256] + b[8]
// ---------------------------------------------------------------------------
__global__ __launch_bounds__(256) void k_conv(const float* __restrict__ x,
                                              const float* __restrict__ w,
                                              const float* __restrict__ bias,
                                              float* __restrict__ y) {
  __shared__ float wl[2048];
  __shared__ float red[4][64][9];
  const int tid = threadIdx.x;
#pragma unroll
  for (int i = 0; i < 8; i++) { int idx = tid + i * 256; wl[idx] = w[idx]; }
  const int bi = blockIdx.x >> 6, row = blockIdx.x & 63;
  const int hwi = tid & 63, cg = tid >> 6;
  const float* xp = x + (((size_t)(bi * 256 + cg * 64)) * 64 + row) * 64 + hwi;
  float acc[8] = {0.f, 0.f, 0.f, 0.f, 0.f, 0.f, 0.f, 0.f};
  __syncthreads();
#pragma unroll 4
  for (int c = 0; c < 64; c++) {
    float v = xp[(size_t)c * 4096];
#pragma unroll
    for (int o = 0; o < 8; o++) acc[o] += v * wl[o * 256 + cg * 64 + c];
  }
#pragma unroll
  for (int o = 0; o < 8; o++) red[cg][hwi][o] = acc[o];
  __syncthreads();
#pragma unroll
  for (int i = 0; i < 2; i++) {
    int p = tid + i * 256; int o = p >> 6, hw = p & 63;
    float sv = red[0][hw][o] + red[1][hw][o] + red[2][hw][o] + red[3][hw][o] + bias[o];
    y[(((size_t)(bi * 8 + o)) * 64 + row) * 64 + hw] = sv;
  }
}

// ---------------------------------------------------------------------------
// K2: bilinear-upsample(64->512) argmax over 8ch, 4x4 mean pool -> fm[4,8,128,128]
// ---------------------------------------------------------------------------
__global__ __launch_bounds__(256) void k_pool(const float* __restrict__ ys,
                                              float* __restrict__ fm) {
  const int g = blockIdx.x * 256 + threadIdx.x;
  const int bi = g >> 14, rem = g & 16383;
  const int sm = rem >> 7, tm = rem & 127;
  int cnt[8] = {0, 0, 0, 0, 0, 0, 0, 0};
  const float* yb = ys + (size_t)bi * 8 * 4096;
#pragma unroll
  for (int py = 0; py < 4; py++) {
    const int s = sm * 4 + py;
    float ph = s * (63.0f / 511.0f); int lh = (int)ph; float wh = ph - (float)lh;
    const int dh = (lh < 63) ? 64 : 0;
#pragma unroll
    for (int px = 0; px < 4; px++) {
      const int t = tm * 4 + px;
      float pw = t * (63.0f / 511.0f); int lt = (int)pw; float wt = pw - (float)lt;
      const int dt = (lt < 63) ? 1 : 0;
      const float w00 = (1.f - wh) * (1.f - wt), w01 = (1.f - wh) * wt;
      const float w10 = wh * (1.f - wt), w11 = wh * wt;
      const int base = lh * 64 + lt;
      float best = 0.f; int am = 0;
#pragma unroll
      for (int c = 0; c < 8; c++) {
        const float* yc = yb + c * 4096 + base;
        float v = w00 * yc[0] + w01 * yc[dt] + w10 * yc[dh] + w11 * yc[dh + dt];
        if (c == 0) { best = v; } else if (v > best) { best = v; am = c; }
      }
#pragma unroll
      for (int c = 0; c < 8; c++) cnt[c] += (am == c);
    }
  }
  const size_t ob = ((size_t)bi * 8) << 14;
#pragma unroll
  for (int c = 0; c < 8; c++)
    fm[ob + ((size_t)c << 14) + (sm << 7) + tm] = (float)cnt[c] * (1.0f / 16.0f);
}

// ---------------------------------------------------------------------------
// K4: per (b,c): corr[4096,64] = A[4096,256] @ B, B[k][p] = U[p][k] = unfold(fm).
// MFMA bf16 16x16x32. Block = 256 thr (4 waves), q-tile 128 (wave: 32q x 64p =
// 2 qfrag x 4 pfrag). U^T staged ONCE in LDS as bf16 (XOR-swizzled, 2-way max)
// -> K-loop has NO barriers (no vmcnt drains: passthrough stores + prefetch
// loads stay in flight). Copy stream (coalesced) also yields per-row nz via
// wave shuffle-reduce (each wave owns whole rows). grid = (32, 32).
// ---------------------------------------------------------------------------
__global__ __launch_bounds__(256) void k_corr(const float* __restrict__ A,
                                              const float* __restrict__ fm,
                                              float* __restrict__ Aout,
                                              float* __restrict__ corr,
                                              float* __restrict__ nzinv) {
  __shared__ unsigned short Ubt[64 * 256];   // bf16 U^T[p][k], rows 512B, XOR-swizzled
  const int tid = threadIdx.x;
  const int bc = blockIdx.y;
  const int qb = blockIdx.x << 7;            // q-tile 128
  const float* Ab = A + ((size_t)bc * 4096 + qb) * 256;
  float* Ob = Aout + ((size_t)bc * 4096 + qb) * 256;
  const float* fmb = fm + ((size_t)bc << 14);

  // ---- stage U^T bf16 (exact: U values are multiples of 1/16) ----
  {
    const int p = tid >> 2, k0 = (tid & 3) << 6;
    const int fmbase = ((k0 >> 4) << 10) + ((p >> 3) << 7) + (p & 7);
    char* ubase = (char*)Ubt + (p << 9);
    const int sw = (p & 7) << 4;
#pragma unroll
    for (int j = 0; j < 64; j += 2) {
      const float v0 = fmb[fmbase + ((j >> 4) << 10) + ((j & 15) << 3)];
      const float v1 = fmb[fmbase + (((j + 1) >> 4) << 10) + (((j + 1) & 15) << 3)];
      *(unsigned*)(ubase + ((((k0 + j) << 1)) ^ sw)) = pk2(v0, v1);
    }
  }
  __syncthreads();   // the ONLY barrier

  const int lane = tid & 63, w = tid >> 6;
  const int m = lane & 15, g = lane >> 4;            // m: row/col-in-frag, g: k-octet
  const float* arow0 = Ab + ((size_t)((w << 5) + m)) * 256 + (g << 3);
  const float* arow1 = arow0 + 16 * 256;
  const char* ub = (const char*)Ubt + ((size_t)m << 9);
  const int sw = (m & 7) << 4;
  const float4* Ab4 = (const float4*)Ab;
  float4* Ob4 = (float4*)Ob;

  f32x4 acc[2][4];
#pragma unroll
  for (int qf = 0; qf < 2; qf++)
#pragma unroll
    for (int pf = 0; pf < 4; pf++) acc[qf][pf] = (f32x4){0.f, 0.f, 0.f, 0.f};

#pragma unroll 2
  for (int c = 0; c < 8; ++c) {
    const int kc = c << 5;
    // copy stream loads (rows 16c..16c+16 of the tile, fully coalesced)
    float4 cp[4];
#pragma unroll
    for (int i = 0; i < 4; i++) cp[i] = Ab4[(c << 10) + (i << 8) + tid];
    // A fragments (16 rows x 32 k per frag; L2-resident gather)
    const float4 a00 = *(const float4*)(arow0 + kc);
    const float4 a01 = *(const float4*)(arow0 + kc + 4);
    const float4 a10 = *(const float4*)(arow1 + kc);
    const float4 a11 = *(const float4*)(arow1 + kc + 4);
    // B fragments from LDS (b128, swizzled; ~2-way = free)
    const int ka = ((c << 6) + (g << 4)) ^ sw;
    short8_t bf0 = *(const short8_t*)(ub + ka);
    short8_t bf1 = *(const short8_t*)(ub + ka + 8192);
    short8_t bf2 = *(const short8_t*)(ub + ka + 16384);
    short8_t bf3 = *(const short8_t*)(ub + ka + 24576);
    // cvt A to bf16 frags
    union { unsigned u[4]; short8_t s; } fa0, fa1;
    fa0.u[0] = pk2(a00.x, a00.y); fa0.u[1] = pk2(a00.z, a00.w);
    fa0.u[2] = pk2(a01.x, a01.y); fa0.u[3] = pk2(a01.z, a01.w);
    fa1.u[0] = pk2(a10.x, a10.y); fa1.u[1] = pk2(a10.z, a10.w);
    fa1.u[2] = pk2(a11.x, a11.y); fa1.u[3] = pk2(a11.z, a11.w);
    acc[0][0] = __builtin_amdgcn_mfma_f32_16x16x32_bf16(fa0.s, bf0, acc[0][0], 0, 0, 0);
    acc[1][0] = __builtin_amdgcn_mfma_f32_16x16x32_bf16(fa1.s, bf0, acc[1][0], 0, 0, 0);
    acc[0][1] = __builtin_amdgcn_mfma_f32_16x16x32_bf16(fa0.s, bf1, acc[0][1], 0, 0, 0);
    acc[1][1] = __builtin_amdgcn_mfma_f32_16x16x32_bf16(fa1.s, bf1, acc[1][1], 0, 0, 0);
    acc[0][2] = __builtin_amdgcn_mfma_f32_16x16x32_bf16(fa0.s, bf2, acc[0][2], 0, 0, 0);
    acc[1][2] = __builtin_amdgcn_mfma_f32_16x16x32_bf16(fa1.s, bf2, acc[1][2], 0, 0, 0);
    acc[0][3] = __builtin_amdgcn_mfma_f32_16x16x32_bf16(fa0.s, bf3, acc[0][3], 0, 0, 0);
    acc[1][3] = __builtin_amdgcn_mfma_f32_16x16x32_bf16(fa1.s, bf3, acc[1][3], 0, 0, 0);
    // passthrough stores (fire-and-forget) + nz counts (wave owns whole rows)
#pragma unroll
    for (int i = 0; i < 4; i++) {
      Ob4[(c << 10) + (i << 8) + tid] = cp[i];
      int c4 = (cp[i].x != 0.f) + (cp[i].y != 0.f) + (cp[i].z != 0.f) + (cp[i].w != 0.f);
      c4 += __shfl_xor(c4, 1);  c4 += __shfl_xor(c4, 2);  c4 += __shfl_xor(c4, 4);
      c4 += __shfl_xor(c4, 8);  c4 += __shfl_xor(c4, 16); c4 += __shfl_xor(c4, 32);
      if (lane == 0) {
        const int row = (c << 4) + (i << 2) + w;
        nzinv[(size_t)bc * 4096 + qb + row] = 1.0f / ((float)c4 + 1e-5f);
      }
    }
  }

  // epilogue: C/D frag layout col = lane&15, row = (lane>>4)*4 + reg
  const int qrow = (w << 5);
#pragma unroll
  for (int qf = 0; qf < 2; qf++) {
    const int q0r = qb + qrow + (qf << 4) + (g << 2);
#pragma unroll
    for (int r = 0; r < 4; r++) {
      float* cb = corr + (((size_t)bc * 4096 + q0r + r) << 6) + m;
      cb[0]  = acc[qf][0][r];
      cb[16] = acc[qf][1][r];
      cb[32] = acc[qf][2][r];
      cb[48] = acc[qf][3][r];
    }
  }
}

// ---------------------------------------------------------------------------
// K5: out = log_softmax_c( (corr*nzinv + 1) * bilinear_up(y_small) )
// ---------------------------------------------------------------------------
__global__ __launch_bounds__(256) void k_out(const float* __restrict__ corr,
                                             const float* __restrict__ nzinv,
                                             const float* __restrict__ ys,
                                             float* __restrict__ out) {
  __shared__ float G[2][8][65];
  const int bx = blockIdx.x;
  const int b = bx >> 8;
  const int s0 = (bx & 255) << 1;
  const int tid = threadIdx.x;
  const float* ysb = ys + ((size_t)b << 15);
#pragma unroll
  for (int j = 0; j < 4; j++) {
    const int e = tid + (j << 8);
    const int sl = e >> 9, c = (e >> 6) & 7, l = e & 63;
    const int s = s0 + sl;
    float ph = s * (63.0f / 511.0f); int lh = (int)ph; float wh = ph - (float)lh;
    const int dh = (lh < 63) ? 64 : 0;
    const float* yc = ysb + ((size_t)c << 12) + lh * 64 + l;
    G[sl][c][l] = (1.f - wh) * yc[0] + wh * yc[dh];
  }
  __syncthreads();

  const int sl = tid >> 7;
  const int s = s0 + sl;
  const int t0 = (tid & 127) << 2;
  const int q = ((s >> 3) << 6) + (t0 >> 3);
  const int p0 = ((s & 7) << 3) + (t0 & 7);

  float z[4][8];
#pragma unroll
  for (int c = 0; c < 8; c++) {
    const size_t bcp = (size_t)(b * 8 + c);
    const float4 cr = *(const float4*)&corr[(((bcp << 12) + q) << 6) + p0];
    const float rz = nzinv[(bcp << 12) + q];
    const float crv[4] = {cr.x, cr.y, cr.z, cr.w};
#pragma unroll
    for (int u = 0; u < 4; u++) {
      const float pw = (t0 + u) * (63.0f / 511.0f);
      const int lt = (int)pw; const float wtt = pw - (float)lt;
      const int hi = (lt < 63) ? lt + 1 : 63;
      const float yv = (1.f - wtt) * G[sl][c][lt] + wtt * G[sl][c][hi];
      z[u][c] = (crv[u] * rz + 1.0f) * yv;
    }
  }
  const size_t ob = ((size_t)b << 21) + ((size_t)s << 9) + t0;
#pragma unroll
  for (int c = 0; c < 8; c++) {
    float4 o;
#pragma unroll
    for (int u = 0; u < 4; u++) {
      float mx = z[u][0];
#pragma unroll
      for (int cc = 1; cc < 8; cc++) mx = fmaxf(mx, z[u][cc]);
      float sum = 0.f;
#pragma unroll
      for (int cc = 0; cc < 8; cc++) sum += __expf(z[u][cc] - mx);
      const float v = z[u][c] - mx - __logf(sum);
      if (u == 0) o.x = v; else if (u == 1) o.y = v; else if (u == 2) o.z = v; else o.w = v;
    }
    *(float4*)&out[ob + ((size_t)c << 18)] = o;
  }
}

// ---------------------------------------------------------------------------
extern "C" void kernel_launch(void* const* d_in, const int* in_sizes, int n_in,
                              void* d_out, int out_size, void* d_ws, size_t ws_size,
                              hipStream_t stream) {
  const float* x   = (const float*)d_in[0];   // [4,256,64,64]
  const float* att = (const float*)d_in[1];   // [4,8,4096,256]
  const float* cw  = (const float*)d_in[2];   // [8,256]
  const float* cb  = (const float*)d_in[3];   // [8]
  float* out1 = (float*)d_out;                          // [4,8,512,512]
  float* out2 = out1 + (size_t)4 * 8 * 512 * 512;       // attentions passthrough
  float* ws = (float*)d_ws;
  float* y_small = ws;                 // 131072  [4,8,64,64]
  float* fm      = ws + 131072;        // 524288  [4,8,128,128]
  float* nzinv   = ws + 655360;        // 131072  [4,8,4096]
  float* corr    = ws + 786432;        // 8388608 [4,8,4096,64]

  k_conv<<<256, 256, 0, stream>>>(x, cw, cb, y_small);
  k_pool<<<256, 256, 0, stream>>>(y_small, fm);
  dim3 g4(32, 32);
  k_corr<<<g4, 256, 0, stream>>>(att, fm, out2, corr, nzinv);
  k_out<<<1024, 256, 0, stream>>>(corr, nzinv, y_small, out1);
}